// Round 1
// baseline (378.835 us; speedup 1.0000x reference)
//
#include <hip/hip_runtime.h>

#define N_NODES 50000
#define N_EDGES 800000
#define IN_DIM 64
#define HID_DIM 64
#define OUT_DIM 16
#define N_RELS 16
#define N_BASES 4

// ---------------------------------------------------------------------------
// Kernel A: Y1[n, o, b] = sum_i feats[n,i] * bases1[b,i,o]
// Layout [N, 64, 4] so the edge kernel reads one float4 per (node, out) pair.
// Block = 256 threads: o = tid&63, sub = tid>>6 (wave id); each wave handles
// 8 nodes of a 32-node tile. feats tile staged in LDS (reads are wave-uniform
// broadcasts -> no bank conflicts). bases1 reads are 256B coalesced per wave.
// ---------------------------------------------------------------------------
__global__ __launch_bounds__(256) void node_xform1(
    const float* __restrict__ feats,   // [N, 64]
    const float* __restrict__ bases1,  // [4, 64, 64]
    float4* __restrict__ Y1) {         // [N, 64] float4
  __shared__ float fl[32 * 64];
  const int tile = blockIdx.x * 32;
  const int tid = threadIdx.x;
  for (int r = 0; r < 8; ++r) {
    int idx = r * 256 + tid;               // 0..2047
    int n = tile + (idx >> 6);
    fl[idx] = (n < N_NODES) ? feats[n * 64 + (idx & 63)] : 0.f;
  }
  __syncthreads();
  const int o = tid & 63, sub = tid >> 6;
  float4 acc[8];
#pragma unroll
  for (int j = 0; j < 8; ++j) acc[j] = make_float4(0.f, 0.f, 0.f, 0.f);
  for (int k = 0; k < 64; ++k) {
    float b0 = bases1[0 * 4096 + k * 64 + o];
    float b1 = bases1[1 * 4096 + k * 64 + o];
    float b2 = bases1[2 * 4096 + k * 64 + o];
    float b3 = bases1[3 * 4096 + k * 64 + o];
#pragma unroll
    for (int j = 0; j < 8; ++j) {
      float f = fl[(sub * 8 + j) * 64 + k];  // wave-uniform -> LDS broadcast
      acc[j].x += f * b0; acc[j].y += f * b1;
      acc[j].z += f * b2; acc[j].w += f * b3;
    }
  }
#pragma unroll
  for (int j = 0; j < 8; ++j) {
    int n = tile + sub * 8 + j;
    if (n < N_NODES) Y1[n * 64 + o] = acc[j];  // coalesced 16B stores
  }
}

// ---------------------------------------------------------------------------
// Edge kernel 1: one wave per edge, lane = output channel o in [0,64).
// msg = norm * dot(coef1[etype], Y1[src, o, :]); atomicAdd into h1[dst, o].
// Y1 gather: 64 lanes x float4 = contiguous 1KB per edge.
// ---------------------------------------------------------------------------
__global__ __launch_bounds__(256) void edge_scatter1(
    const int* __restrict__ src, const int* __restrict__ dst,
    const int* __restrict__ etype, const float* __restrict__ enorm,
    const float4* __restrict__ coef1,  // [16]
    const float4* __restrict__ Y1,     // [N*64]
    float* __restrict__ h1) {          // [N, 64]
  const int tid = threadIdx.x;
  const int e = blockIdx.x * 4 + (tid >> 6);
  const int lane = tid & 63;
  if (e >= N_EDGES) return;
  const int s = src[e], d = dst[e], t = etype[e];
  const float nm = enorm[e];
  const float4 c = coef1[t];
  const float4 y = Y1[s * 64 + lane];
  const float m = nm * (c.x * y.x + c.y * y.y + c.z * y.z + c.w * y.w);
  atomicAdd(&h1[d * 64 + lane], m);
}

// ---------------------------------------------------------------------------
// Kernel C: h = relu(h1 + bias1) fused with Y2[n, o, b] = sum_k h[n,k]*bases2[b,k,o]
// Block = 256: o = tid&15, sub = tid>>4; each sub handles 2 nodes of a
// 32-node tile. LDS stride 65 breaks the 4-address same-bank conflict.
// ---------------------------------------------------------------------------
__global__ __launch_bounds__(256) void node_xform2(
    const float* __restrict__ h1raw,   // [N, 64] (pre-activation scatter sum)
    const float* __restrict__ bias1,   // [64]
    const float* __restrict__ bases2,  // [4, 64, 16]
    float4* __restrict__ Y2) {         // [N, 16] float4
  __shared__ float hl[32 * 65];
  const int tile = blockIdx.x * 32;
  const int tid = threadIdx.x;
  for (int r = 0; r < 8; ++r) {
    int idx = r * 256 + tid;
    int n = tile + (idx >> 6), k = idx & 63;
    float v = (n < N_NODES) ? h1raw[n * 64 + k] + bias1[k] : 0.f;
    hl[(idx >> 6) * 65 + k] = fmaxf(v, 0.f);
  }
  __syncthreads();
  const int o = tid & 15, sub = tid >> 4;
  float4 acc[2] = {make_float4(0.f, 0.f, 0.f, 0.f), make_float4(0.f, 0.f, 0.f, 0.f)};
  for (int k = 0; k < 64; ++k) {
    float b0 = bases2[0 * 1024 + k * 16 + o];
    float b1 = bases2[1 * 1024 + k * 16 + o];
    float b2 = bases2[2 * 1024 + k * 16 + o];
    float b3 = bases2[3 * 1024 + k * 16 + o];
#pragma unroll
    for (int j = 0; j < 2; ++j) {
      float f = hl[(sub * 2 + j) * 65 + k];
      acc[j].x += f * b0; acc[j].y += f * b1;
      acc[j].z += f * b2; acc[j].w += f * b3;
    }
  }
#pragma unroll
  for (int j = 0; j < 2; ++j) {
    int n = tile + sub * 2 + j;
    if (n < N_NODES) Y2[n * 16 + o] = acc[j];
  }
}

// ---------------------------------------------------------------------------
// Edge kernel 2: 16 output channels -> 4 edges per wave.
// lane = tid&63; edge sub = lane>>4, o = lane&15. Gathers 256B per edge.
// Accumulates directly into d_out (zeroed beforehand).
// ---------------------------------------------------------------------------
__global__ __launch_bounds__(256) void edge_scatter2(
    const int* __restrict__ src, const int* __restrict__ dst,
    const int* __restrict__ etype, const float* __restrict__ enorm,
    const float4* __restrict__ coef2,  // [16]
    const float4* __restrict__ Y2,     // [N*16]
    float* __restrict__ out) {         // [N, 16]
  const int tid = threadIdx.x;
  const int e = blockIdx.x * 16 + (tid >> 4);
  const int o = tid & 15;
  if (e >= N_EDGES) return;
  const int s = src[e], d = dst[e], t = etype[e];
  const float nm = enorm[e];
  const float4 c = coef2[t];
  const float4 y = Y2[s * 16 + o];
  const float m = nm * (c.x * y.x + c.y * y.y + c.z * y.z + c.w * y.w);
  atomicAdd(&out[d * 16 + o], m);
}

// ---------------------------------------------------------------------------
// Final epilogue: out = relu(out + bias2), in-place, float4 vectorized.
// ---------------------------------------------------------------------------
__global__ __launch_bounds__(256) void bias_relu_out(
    float4* __restrict__ out, const float4* __restrict__ bias2) {
  const int i = blockIdx.x * 256 + threadIdx.x;  // over N*16/4 = 200000
  if (i < N_NODES * OUT_DIM / 4) {
    float4 v = out[i];
    float4 b = bias2[i & 3];  // OUT_DIM=16 -> 4 float4s, period 4
    v.x = fmaxf(v.x + b.x, 0.f);
    v.y = fmaxf(v.y + b.y, 0.f);
    v.z = fmaxf(v.z + b.z, 0.f);
    v.w = fmaxf(v.w + b.w, 0.f);
    out[i] = v;
  }
}

extern "C" void kernel_launch(void* const* d_in, const int* in_sizes, int n_in,
                              void* d_out, int out_size, void* d_ws, size_t ws_size,
                              hipStream_t stream) {
  const float* feats  = (const float*)d_in[0];
  const int*   src    = (const int*)d_in[1];
  const int*   dst    = (const int*)d_in[2];
  const int*   etype  = (const int*)d_in[3];
  const float* enorm  = (const float*)d_in[4];
  const float* bases1 = (const float*)d_in[5];
  const float* coef1  = (const float*)d_in[6];
  const float* bias1  = (const float*)d_in[7];
  const float* bases2 = (const float*)d_in[8];
  const float* coef2  = (const float*)d_in[9];
  const float* bias2  = (const float*)d_in[10];
  float* out = (float*)d_out;

  // Workspace layout (fp32 counts): Y1 [N*256] | h1 [N*64] | Y2 [N*64]
  float* Y1 = (float*)d_ws;
  float* h1 = Y1 + (size_t)N_NODES * 256;
  float* Y2 = h1 + (size_t)N_NODES * 64;

  // Zero the scatter accumulators (ws/out are re-poisoned before each call).
  hipMemsetAsync(h1, 0, (size_t)N_NODES * 64 * sizeof(float), stream);
  hipMemsetAsync(out, 0, (size_t)N_NODES * 16 * sizeof(float), stream);

  const int node_blocks = (N_NODES + 31) / 32;
  node_xform1<<<node_blocks, 256, 0, stream>>>(feats, bases1, (float4*)Y1);
  edge_scatter1<<<N_EDGES / 4, 256, 0, stream>>>(src, dst, etype, enorm,
                                                 (const float4*)coef1,
                                                 (const float4*)Y1, h1);
  node_xform2<<<node_blocks, 256, 0, stream>>>(h1, bias1, bases2, (float4*)Y2);
  edge_scatter2<<<N_EDGES / 16, 256, 0, stream>>>(src, dst, etype, enorm,
                                                  (const float4*)coef2,
                                                  (const float4*)Y2, out);
  bias_relu_out<<<(N_NODES * OUT_DIM / 4 + 255) / 256, 256, 0, stream>>>(
      (float4*)out, (const float4*)bias2);
}